// Round 4
// baseline (4621.343 us; speedup 1.0000x reference)
//
#include <hip/hip_runtime.h>
#include <math.h>

typedef unsigned short u16;
typedef unsigned int u32;

// dims
#define NB 4
#define NT 256
#define NN 48
#define NF 4
#define NH 64
#define NK 4
#define NE 192
#define NLH 512
#define NC 8
#define NG 1024          // B*T
#define KH 256           // K*H
#define SEQD 3072        // N*H
#define G4 2048          // 4*LH
#define LSTM_NBLK 64

__device__ __forceinline__ float bf2f(u16 v) {
  union { u32 u; float f; } c; c.u = ((u32)v) << 16; return c.f;
}
__device__ __forceinline__ u16 f2bf(float f) {
  union { float f; u32 u; } c; c.f = f;
  u32 r = c.u + 0x7FFFu + ((c.u >> 16) & 1u);
  return (u16)(r >> 16);
}

// ---------------- kernel 0: CSR build (by dst) + barrier zero ----------------
__global__ void setup_kernel(const int* __restrict__ ei, int* __restrict__ coff,
                             int* __restrict__ ceid, u32* __restrict__ bar)
{
  if (threadIdx.x == 0 && blockIdx.x == 0) {
    bar[0] = 0u; bar[1] = 0u;
    int cnt[NN];
    for (int n = 0; n < NN; ++n) cnt[n] = 0;
    for (int e = 0; e < NE; ++e) cnt[ei[NE + e]]++;
    coff[0] = 0;
    for (int n = 0; n < NN; ++n) coff[n + 1] = coff[n] + cnt[n];
    int pos[NN];
    for (int n = 0; n < NN; ++n) pos[n] = coff[n];
    for (int e = 0; e < NE; ++e) { int d = ei[NE + e]; ceid[pos[d]++] = e; }
  }
}

// ---------------- kernel 0b: transpose Wl2/Wr2 -> [out][in] (f32) -----------
__global__ void transpose_kernel(const float* __restrict__ Wl2, const float* __restrict__ Wr2,
                                 float* __restrict__ WlT, float* __restrict__ WrT)
{
  int id0 = blockIdx.x * 256 + threadIdx.x;
  for (int rep = 0; rep < 2; ++rep) {
    int id = id0 + rep * 32768;               // id = o*256 + i
    int o = id >> 8, i = id & 255;
    WlT[id] = Wl2[i * 256 + o];
    WrT[id] = Wr2[i * 256 + o];
  }
}

// ---------------- kernel 1: fused GATv2 layer1+layer2 (one block per graph) --
// All-f32 except xl/xr packed bf16 in LDS (fits 64KB static limit).
__global__ __launch_bounds__(256) void gat_fused_kernel(
    const float* __restrict__ x, const int* __restrict__ ei,
    const int* __restrict__ coff, const int* __restrict__ ceid,
    const float* __restrict__ Wl1, const float* __restrict__ Wr1,
    const float* __restrict__ att1, const float* __restrict__ b1,
    const float* __restrict__ WlT, const float* __restrict__ WrT,
    const float* __restrict__ att2, const float* __restrict__ b2,
    float* __restrict__ h2)
{
  __shared__ float sA[NN * KH];          // 48KB: h1 (f32), later xl|xr (bf16)
  __shared__ float sWl1[NF * KH], sWr1[NF * KH];   // 4KB + 4KB
  __shared__ float satt[KH];             // att1 then att2
  __shared__ float sbias[KH];            // b1 then b2
  __shared__ float sx[NN * NF];          // 768B
  __shared__ float esc[NE * NK];         // 3KB
  __shared__ int soff[NN + 1];           // 196B
  __shared__ u16 seid[NE], ssrc[NE], sdst[NE];   // 3*384B

  const int tid = threadIdx.x;
  const int g = blockIdx.x;

  // ---- stage phase-1 constants ----
#pragma unroll
  for (int rep = 0; rep < 4; ++rep) {
    int idx = rep * 256 + tid;
    sWl1[idx] = Wl1[idx];
    sWr1[idx] = Wr1[idx];
  }
  satt[tid] = att1[tid];
  sbias[tid] = b1[tid];
  if (tid < NN * NF) sx[tid] = x[(size_t)g * (NN * NF) + tid];
  if (tid < NE) {
    ssrc[tid] = (u16)ei[tid];
    sdst[tid] = (u16)ei[NE + tid];
    seid[tid] = (u16)ceid[tid];
  }
  if (tid < NN + 1) soff[tid] = coff[tid];
  __syncthreads();

  // ---- phase 2: layer-1 edge scores ----
  for (int task = tid; task < NE * NK; task += 256) {
    int e = task >> 2, k = task & 3;
    int s = ssrc[e], d = sdst[e];
    float xs0 = sx[s * 4 + 0], xs1 = sx[s * 4 + 1], xs2 = sx[s * 4 + 2], xs3 = sx[s * 4 + 3];
    float xd0 = sx[d * 4 + 0], xd1 = sx[d * 4 + 1], xd2 = sx[d * 4 + 2], xd3 = sx[d * 4 + 3];
    float acc = 0.f;
    int ob = k * 64;
    for (int h = 0; h < 64; ++h) {
      int o = ob + h;
      float xl = fmaf(xs3, sWl1[768 + o], fmaf(xs2, sWl1[512 + o],
                 fmaf(xs1, sWl1[256 + o], xs0 * sWl1[o])));
      float xr = fmaf(xd3, sWr1[768 + o], fmaf(xd2, sWr1[512 + o],
                 fmaf(xd1, sWr1[256 + o], xd0 * sWr1[o])));
      float tv = xl + xr;
      tv = tv > 0.f ? tv : 0.2f * tv;
      acc = fmaf(tv, satt[o], acc);
    }
    esc[e * 4 + k] = acc;
  }
  __syncthreads();

  // ---- phase 3: layer-1 softmax per (n,k) ----
  if (tid < NN * NK) {
    int n = tid >> 2, k = tid & 3;
    int e0 = soff[n], e1 = soff[n + 1];
    if (e1 > e0) {
      float m = -1e30f;
      for (int j = e0; j < e1; ++j) m = fmaxf(m, esc[seid[j] * 4 + k]);
      float den = 0.f;
      for (int j = e0; j < e1; ++j) {
        float pv = expf(esc[seid[j] * 4 + k] - m);
        esc[seid[j] * 4 + k] = pv;
        den += pv;
      }
      float inv = 1.f / (den + 1e-16f);
      for (int j = e0; j < e1; ++j) esc[seid[j] * 4 + k] *= inv;
    }
  }
  __syncthreads();

  // ---- phase 4: layer-1 aggregate -> h1 into sA (f32); reload att2 ----
  satt[tid] = att2[tid];   // att1 dead (sync above separates)
  {
    int o = tid, k = o >> 6;
    float w0 = sWl1[o], w1 = sWl1[256 + o], w2 = sWl1[512 + o], w3 = sWl1[768 + o];
    for (int n = 0; n < NN; ++n) {
      int e0 = soff[n], e1 = soff[n + 1];
      float acc = 0.f;
      for (int j = e0; j < e1; ++j) {
        int e = seid[j];
        int s = ssrc[e];
        float xl = fmaf(sx[s * 4 + 3], w3, fmaf(sx[s * 4 + 2], w2,
                   fmaf(sx[s * 4 + 1], w1, sx[s * 4 + 0] * w0)));
        acc = fmaf(esc[e * 4 + k], xl, acc);
      }
      float ov = acc + sbias[o];
      sA[n * KH + o] = fmaxf(ov, 0.f);   // relu(h1)
    }
  }
  __syncthreads();
  if (tid < NH) sbias[tid] = b2[tid];   // b1 dead

  // ---- phase 5: layer-2 transforms: thread owns output column o = tid ----
  float axl[NN], axr[NN];
#pragma unroll
  for (int n = 0; n < NN; ++n) { axl[n] = 0.f; axr[n] = 0.f; }
  {
    const float* wlr = WlT + (size_t)tid * 256;
    const float* wrr = WrT + (size_t)tid * 256;
    for (int ic = 0; ic < 32; ++ic) {
      const float4* wl4 = (const float4*)(wlr + ic * 8);
      const float4* wr4 = (const float4*)(wrr + ic * 8);
      float4 la = wl4[0], lb = wl4[1], ra = wr4[0], rb = wr4[1];
      float wl[8] = {la.x, la.y, la.z, la.w, lb.x, lb.y, lb.z, lb.w};
      float wr[8] = {ra.x, ra.y, ra.z, ra.w, rb.x, rb.y, rb.z, rb.w};
#pragma unroll
      for (int n = 0; n < NN; ++n) {
        const float4* hp = (const float4*)&sA[n * 256 + ic * 8];
        float4 ha = hp[0], hb = hp[1];
        float hv[8] = {ha.x, ha.y, ha.z, ha.w, hb.x, hb.y, hb.z, hb.w};
#pragma unroll
        for (int q = 0; q < 8; ++q) {
          axl[n] = fmaf(hv[q], wl[q], axl[n]);
          axr[n] = fmaf(hv[q], wr[q], axr[n]);
        }
      }
    }
  }
  __syncthreads();
  // overwrite sA region with bf16 xl | xr (exactly 49152 B)
  u16* xlb = (u16*)sA;
  u16* xrb = xlb + NN * KH;
#pragma unroll
  for (int n = 0; n < NN; ++n) {
    xlb[n * 256 + tid] = f2bf(axl[n]);
    xrb[n * 256 + tid] = f2bf(axr[n]);
  }
  __syncthreads();

  // ---- phase 6: layer-2 edge scores ----
  for (int task = tid; task < NE * NK; task += 256) {
    int e = task >> 2, k = task & 3;
    int s = ssrc[e], d = sdst[e];
    const u16* xls = xlb + s * 256 + k * 64;
    const u16* xrd = xrb + d * 256 + k * 64;
    const float* ap = satt + k * 64;
    float acc = 0.f;
    for (int h = 0; h < 64; ++h) {
      float tv = bf2f(xls[h]) + bf2f(xrd[h]);
      tv = tv > 0.f ? tv : 0.2f * tv;
      acc = fmaf(tv, ap[h], acc);
    }
    esc[e * 4 + k] = acc;
  }
  __syncthreads();

  // ---- phase 7: layer-2 softmax ----
  if (tid < NN * NK) {
    int n = tid >> 2, k = tid & 3;
    int e0 = soff[n], e1 = soff[n + 1];
    if (e1 > e0) {
      float m = -1e30f;
      for (int j = e0; j < e1; ++j) m = fmaxf(m, esc[seid[j] * 4 + k]);
      float den = 0.f;
      for (int j = e0; j < e1; ++j) {
        float pv = expf(esc[seid[j] * 4 + k] - m);
        esc[seid[j] * 4 + k] = pv;
        den += pv;
      }
      float inv = 1.f / (den + 1e-16f);
      for (int j = e0; j < e1; ++j) esc[seid[j] * 4 + k] *= inv;
    }
  }
  __syncthreads();

  // ---- phase 8: layer-2 aggregate, mean over k, +bias, relu -> h2 (f32) ----
  for (int task = tid; task < NN * NH; task += 256) {
    int n = task >> 6, h = task & 63;
    int e0 = soff[n], e1 = soff[n + 1];
    float acc = 0.f;
    for (int j = e0; j < e1; ++j) {
      int e = seid[j];
      int s = ssrc[e];
      const u16* xls = xlb + s * 256 + h;
#pragma unroll
      for (int k = 0; k < 4; ++k)
        acc = fmaf(esc[e * 4 + k], bf2f(xls[k * 64]), acc);
    }
    float ov = fmaf(acc, 0.25f, sbias[h]);
    h2[(size_t)g * SEQD + task] = fmaxf(ov, 0.f);
  }
}

// ---------------- kernel 3: xw = seq @ W_ih^T + (b_ih+b_hh), all f32 --------
// 64g x 64r tile, 256 threads; grid = 16 gtiles * 32 rtiles = 512 blocks.
// LDS: sseq 24KB + sw 24KB = 48KB.
__global__ __launch_bounds__(256) void xw_kernel(const float* __restrict__ h2,
                                                 const float* __restrict__ Wih,
                                                 const float* __restrict__ bih,
                                                 const float* __restrict__ bhh,
                                                 float* __restrict__ xw)
{
  __shared__ float sseq[96 * 64];   // [i][g]
  __shared__ float sw[96 * 64];     // [i][r]
  const int tid = threadIdx.x;
  const int gt = blockIdx.x & 15;
  const int rt = blockIdx.x >> 4;
  const int g0 = gt * 64, r0 = rt * 64;
  const int r = tid & 63, gsub = tid >> 6;   // gsub<4, 16 g each
  const int R = r0 + r;
  const int lane = tid & 63, qi = tid >> 6;  // staging: 4 chunks x 24 i
  float acc[16];
#pragma unroll
  for (int j = 0; j < 16; ++j) acc[j] = 0.f;

  for (int ic = 0; ic < 32; ++ic) {
    __syncthreads();
    {
      const float* src = h2 + (size_t)(g0 + lane) * SEQD + ic * 96 + qi * 24;
#pragma unroll
      for (int q = 0; q < 24; ++q) sseq[(qi * 24 + q) * 64 + lane] = src[q];
    }
    {
      const float* wsrc = Wih + (size_t)(r0 + lane) * SEQD + ic * 96 + qi * 24;
#pragma unroll
      for (int q = 0; q < 24; ++q) sw[(qi * 24 + q) * 64 + lane] = wsrc[q];
    }
    __syncthreads();
    for (int i = 0; i < 96; ++i) {
      float wv = sw[i * 64 + r];
      const float4* sp = (const float4*)&sseq[i * 64 + gsub * 16];
      float4 s0 = sp[0], s1 = sp[1], s2 = sp[2], s3 = sp[3];
      float sv[16] = {s0.x, s0.y, s0.z, s0.w, s1.x, s1.y, s1.z, s1.w,
                      s2.x, s2.y, s2.z, s2.w, s3.x, s3.y, s3.z, s3.w};
#pragma unroll
      for (int j = 0; j < 16; ++j) acc[j] = fmaf(sv[j], wv, acc[j]);
    }
  }
  const float bias = bih[R] + bhh[R];
#pragma unroll
  for (int j = 0; j < 16; ++j) {
    int g = g0 + gsub * 16 + j;
    xw[(size_t)g * G4 + R] = acc[j] + bias;
  }
}

// ---------------- kernel 4: persistent LSTM + FC (all f32) ----------------
__device__ __forceinline__ void grid_barrier(u32* bar) {
  __threadfence();
  __syncthreads();
  if (threadIdx.x == 0) {
    u32 gen = __hip_atomic_load(&bar[1], __ATOMIC_RELAXED, __HIP_MEMORY_SCOPE_AGENT);
    u32 a = __hip_atomic_fetch_add(&bar[0], 1u, __ATOMIC_ACQ_REL, __HIP_MEMORY_SCOPE_AGENT);
    if (a == (u32)(LSTM_NBLK - 1)) {
      __hip_atomic_store(&bar[0], 0u, __ATOMIC_RELAXED, __HIP_MEMORY_SCOPE_AGENT);
      __hip_atomic_fetch_add(&bar[1], 1u, __ATOMIC_RELEASE, __HIP_MEMORY_SCOPE_AGENT);
    } else {
      while (__hip_atomic_load(&bar[1], __ATOMIC_ACQUIRE, __HIP_MEMORY_SCOPE_AGENT) == gen) {}
    }
  }
  __syncthreads();
  __threadfence();
}

// 64 blocks x 256 threads, plain launch (stream drained before this kernel,
// so all 64 blocks are trivially co-resident on 256 CUs).
__global__ __launch_bounds__(256) void lstm_kernel(const float* __restrict__ xw,
                                                   const float* __restrict__ Whh,
                                                   const float* __restrict__ fcw,
                                                   const float* __restrict__ fcb,
                                                   float* __restrict__ hbuf,
                                                   u32* __restrict__ bar,
                                                   float* __restrict__ out)
{
  __shared__ float hlds[NB * NLH];     // 8KB
  __shared__ float part[8][32][4];
  __shared__ float gv[32][4];
  __shared__ float clds[8][4];
  __shared__ float fcpart[32][8];

  const int tid = threadIdx.x;
  const int blk = blockIdx.x;
  const int r32 = tid & 31, p = tid >> 5;
  const int R = (r32 >> 3) * NLH + blk * 8 + (r32 & 7);  // gate row owned

  float wreg[64];                       // Whh row R, segment p*64..p*64+63 (f32)
  {
    const float4* wsrc = (const float4*)(Whh + (size_t)R * NLH + p * 64);
#pragma unroll
    for (int q = 0; q < 16; ++q) {
      float4 v = wsrc[q];
      wreg[4 * q + 0] = v.x; wreg[4 * q + 1] = v.y;
      wreg[4 * q + 2] = v.z; wreg[4 * q + 3] = v.w;
    }
  }
  if (tid < 32) {
    int u = tid & 7, b = tid >> 3;
    clds[u][b] = 0.f;
    hbuf[0 * (NB * NLH) + b * NLH + blk * 8 + u] = 0.f;
  }
  grid_barrier(bar);

  for (int t = 0; t < NT; ++t) {
    const float* hprev = hbuf + (t & 1) * (NB * NLH);
#pragma unroll
    for (int w = 0; w < 8; ++w) { int idx = w * 256 + tid; hlds[idx] = hprev[idx]; }
    float myxw = 0.f;
    if (tid < 128) {
      int rrx = tid & 31, b = tid >> 5;
      int Rx = (rrx >> 3) * NLH + blk * 8 + (rrx & 7);
      myxw = xw[(size_t)(b * NT + t) * G4 + Rx];
    }
    __syncthreads();

    float a0 = 0.f, a1 = 0.f, a2 = 0.f, a3 = 0.f;
    const float* h0 = &hlds[0 * NLH + p * 64];
    const float* h1p = &hlds[1 * NLH + p * 64];
    const float* h2p = &hlds[2 * NLH + p * 64];
    const float* h3p = &hlds[3 * NLH + p * 64];
#pragma unroll
    for (int j = 0; j < 16; ++j) {
      float w0 = wreg[4 * j], w1 = wreg[4 * j + 1], w2 = wreg[4 * j + 2], w3 = wreg[4 * j + 3];
      float4 v0 = *(const float4*)(h0 + 4 * j);
      float4 v1 = *(const float4*)(h1p + 4 * j);
      float4 v2 = *(const float4*)(h2p + 4 * j);
      float4 v3 = *(const float4*)(h3p + 4 * j);
      a0 = fmaf(v0.w, w3, fmaf(v0.z, w2, fmaf(v0.y, w1, fmaf(v0.x, w0, a0))));
      a1 = fmaf(v1.w, w3, fmaf(v1.z, w2, fmaf(v1.y, w1, fmaf(v1.x, w0, a1))));
      a2 = fmaf(v2.w, w3, fmaf(v2.z, w2, fmaf(v2.y, w1, fmaf(v2.x, w0, a2))));
      a3 = fmaf(v3.w, w3, fmaf(v3.z, w2, fmaf(v3.y, w1, fmaf(v3.x, w0, a3))));
    }
    part[p][r32][0] = a0; part[p][r32][1] = a1;
    part[p][r32][2] = a2; part[p][r32][3] = a3;
    __syncthreads();
    if (tid < 128) {
      int rrx = tid & 31, b = tid >> 5;
      float s = myxw;
#pragma unroll
      for (int pp = 0; pp < 8; ++pp) s += part[pp][rrx][b];
      gv[rrx][b] = s;
    }
    __syncthreads();
    if (tid < 32) {
      int u = tid & 7, b = tid >> 3;
      float gi = gv[0 + u][b], gf = gv[8 + u][b], gg = gv[16 + u][b], go = gv[24 + u][b];
      float si = 1.f / (1.f + expf(-gi));
      float sf = 1.f / (1.f + expf(-gf));
      float so = 1.f / (1.f + expf(-go));
      float cn = fmaf(sf, clds[u][b], si * tanhf(gg));
      float hn = so * tanhf(cn);
      clds[u][b] = cn;
      hbuf[((t + 1) & 1) * (NB * NLH) + b * NLH + blk * 8 + u] = hn;
    }
    grid_barrier(bar);
  }

  // FC on block 0; final h is in hbuf[0] (NT even)
  if (blk == 0) {
    int pr = tid >> 3, l = tid & 7;
    int b = pr >> 3, cc = pr & 7;
    const float* hf = hbuf + b * NLH;
    float a = 0.f;
    int base = cc * NLH + l * 64;
    for (int j = 0; j < 64; ++j) a = fmaf(hf[l * 64 + j], fcw[base + j], a);
    fcpart[pr][l] = a;
    __syncthreads();
    if (tid < 32) {
      float s = fcb[tid & 7];
#pragma unroll
      for (int l2 = 0; l2 < 8; ++l2) s += fcpart[tid][l2];
      out[tid] = s;          // f32 output, matches reference output dtype
    }
  }
}

// ---------------- host ----------------
extern "C" void kernel_launch(void* const* d_in, const int* in_sizes, int n_in,
                              void* d_out, int out_size, void* d_ws, size_t ws_size,
                              hipStream_t stream)
{
  (void)in_sizes; (void)n_in; (void)out_size; (void)ws_size;
  const float* x    = (const float*)d_in[0];
  const int*   ei   = (const int*)d_in[1];
  const float* Wl1  = (const float*)d_in[2];
  const float* Wr1  = (const float*)d_in[3];
  const float* att1 = (const float*)d_in[4];
  const float* b1   = (const float*)d_in[5];
  const float* Wl2  = (const float*)d_in[6];
  const float* Wr2  = (const float*)d_in[7];
  const float* att2 = (const float*)d_in[8];
  const float* b2   = (const float*)d_in[9];
  const float* Wih  = (const float*)d_in[10];
  const float* Whh  = (const float*)d_in[11];
  const float* bih  = (const float*)d_in[12];
  const float* bhh  = (const float*)d_in[13];
  const float* fcw  = (const float*)d_in[14];
  const float* fcb  = (const float*)d_in[15];

  // workspace layout (~21.5 MB)
  char* ws = (char*)d_ws;
  int* csr_off = (int*)(ws + 0);                    // 49 ints
  int* csr_eid = (int*)(ws + 256);                  // 192 ints -> ends 1024
  u32* bar     = (u32*)(ws + 1024);                 // 2 u32
  float* WlT   = (float*)(ws + 4096);               // 256 KB -> 266240
  float* WrT   = (float*)(ws + 266240);             // 256 KB -> 528384
  float* h2    = (float*)(ws + 528384);             // 12 MB  -> 13111296
  float* xwb   = (float*)(ws + 13111296);           // 8 MB   -> 21499904
  float* hbuf  = (float*)(ws + 21499904);           // 16 KB  -> 21516288
  float* outp  = (float*)d_out;

  setup_kernel<<<1, 64, 0, stream>>>(ei, csr_off, csr_eid, bar);
  transpose_kernel<<<128, 256, 0, stream>>>(Wl2, Wr2, WlT, WrT);
  gat_fused_kernel<<<NG, 256, 0, stream>>>(x, ei, csr_off, csr_eid,
                                           Wl1, Wr1, att1, b1,
                                           WlT, WrT, att2, b2, h2);
  xw_kernel<<<512, 256, 0, stream>>>(h2, Wih, bih, bhh, xwb);
  lstm_kernel<<<LSTM_NBLK, 256, 0, stream>>>(xwb, Whh, fcw, fcb, hbuf, bar, outp);
}

// Round 5
// 2287.516 us; speedup vs baseline: 2.0202x; 2.0202x over previous
//
#include <hip/hip_runtime.h>
#include <math.h>

typedef unsigned short u16;
typedef unsigned int u32;

// dims
#define NB 4
#define NT 256
#define NN 48
#define NF 4
#define NH 64
#define NK 4
#define NE 192
#define NLH 512
#define NC 8
#define NG 1024          // B*T
#define KH 256           // K*H
#define SEQD 3072        // N*H
#define G4 2048          // 4*LH
#define LSTM_NBLK 64
#define FLAG_STRIDE 16   // 64B between flags (one cacheline each)

__device__ __forceinline__ float bf2f(u16 v) {
  union { u32 u; float f; } c; c.u = ((u32)v) << 16; return c.f;
}
__device__ __forceinline__ u16 f2bf(float f) {
  union { float f; u32 u; } c; c.f = f;
  u32 r = c.u + 0x7FFFu + ((c.u >> 16) & 1u);
  return (u16)(r >> 16);
}

// ---------------- kernel 0: CSR build (by dst) + flag init ----------------
__global__ void setup_kernel(const int* __restrict__ ei, int* __restrict__ coff,
                             int* __restrict__ ceid, int* __restrict__ flags)
{
  if (threadIdx.x < LSTM_NBLK)
    __hip_atomic_store(&flags[threadIdx.x * FLAG_STRIDE], -1,
                       __ATOMIC_RELAXED, __HIP_MEMORY_SCOPE_AGENT);
  if (threadIdx.x == 0 && blockIdx.x == 0) {
    int cnt[NN];
    for (int n = 0; n < NN; ++n) cnt[n] = 0;
    for (int e = 0; e < NE; ++e) cnt[ei[NE + e]]++;
    coff[0] = 0;
    for (int n = 0; n < NN; ++n) coff[n + 1] = coff[n] + cnt[n];
    int pos[NN];
    for (int n = 0; n < NN; ++n) pos[n] = coff[n];
    for (int e = 0; e < NE; ++e) { int d = ei[NE + e]; ceid[pos[d]++] = e; }
  }
}

// ---------------- kernel 0b: transpose Wl2/Wr2 -> [out][in] (f32) -----------
__global__ void transpose_kernel(const float* __restrict__ Wl2, const float* __restrict__ Wr2,
                                 float* __restrict__ WlT, float* __restrict__ WrT)
{
  int id0 = blockIdx.x * 256 + threadIdx.x;
  for (int rep = 0; rep < 2; ++rep) {
    int id = id0 + rep * 32768;               // id = o*256 + i
    int o = id >> 8, i = id & 255;
    WlT[id] = Wl2[i * 256 + o];
    WrT[id] = Wr2[i * 256 + o];
  }
}

// ---------------- kernel 1: fused GATv2 layer1+layer2 (one block per graph) --
// All-f32 except xl/xr packed bf16 in LDS (fits 64KB static limit).
__global__ __launch_bounds__(256) void gat_fused_kernel(
    const float* __restrict__ x, const int* __restrict__ ei,
    const int* __restrict__ coff, const int* __restrict__ ceid,
    const float* __restrict__ Wl1, const float* __restrict__ Wr1,
    const float* __restrict__ att1, const float* __restrict__ b1,
    const float* __restrict__ WlT, const float* __restrict__ WrT,
    const float* __restrict__ att2, const float* __restrict__ b2,
    float* __restrict__ h2)
{
  __shared__ float sA[NN * KH];          // 48KB: h1 (f32), later xl|xr (bf16)
  __shared__ float sWl1[NF * KH], sWr1[NF * KH];   // 4KB + 4KB
  __shared__ float satt[KH];             // att1 then att2
  __shared__ float sbias[KH];            // b1 then b2
  __shared__ float sx[NN * NF];          // 768B
  __shared__ float esc[NE * NK];         // 3KB
  __shared__ int soff[NN + 1];           // 196B
  __shared__ u16 seid[NE], ssrc[NE], sdst[NE];   // 3*384B

  const int tid = threadIdx.x;
  const int g = blockIdx.x;

  // ---- stage phase-1 constants ----
#pragma unroll
  for (int rep = 0; rep < 4; ++rep) {
    int idx = rep * 256 + tid;
    sWl1[idx] = Wl1[idx];
    sWr1[idx] = Wr1[idx];
  }
  satt[tid] = att1[tid];
  sbias[tid] = b1[tid];
  if (tid < NN * NF) sx[tid] = x[(size_t)g * (NN * NF) + tid];
  if (tid < NE) {
    ssrc[tid] = (u16)ei[tid];
    sdst[tid] = (u16)ei[NE + tid];
    seid[tid] = (u16)ceid[tid];
  }
  if (tid < NN + 1) soff[tid] = coff[tid];
  __syncthreads();

  // ---- phase 2: layer-1 edge scores ----
  for (int task = tid; task < NE * NK; task += 256) {
    int e = task >> 2, k = task & 3;
    int s = ssrc[e], d = sdst[e];
    float xs0 = sx[s * 4 + 0], xs1 = sx[s * 4 + 1], xs2 = sx[s * 4 + 2], xs3 = sx[s * 4 + 3];
    float xd0 = sx[d * 4 + 0], xd1 = sx[d * 4 + 1], xd2 = sx[d * 4 + 2], xd3 = sx[d * 4 + 3];
    float acc = 0.f;
    int ob = k * 64;
    for (int h = 0; h < 64; ++h) {
      int o = ob + h;
      float xl = fmaf(xs3, sWl1[768 + o], fmaf(xs2, sWl1[512 + o],
                 fmaf(xs1, sWl1[256 + o], xs0 * sWl1[o])));
      float xr = fmaf(xd3, sWr1[768 + o], fmaf(xd2, sWr1[512 + o],
                 fmaf(xd1, sWr1[256 + o], xd0 * sWr1[o])));
      float tv = xl + xr;
      tv = tv > 0.f ? tv : 0.2f * tv;
      acc = fmaf(tv, satt[o], acc);
    }
    esc[e * 4 + k] = acc;
  }
  __syncthreads();

  // ---- phase 3: layer-1 softmax per (n,k) ----
  if (tid < NN * NK) {
    int n = tid >> 2, k = tid & 3;
    int e0 = soff[n], e1 = soff[n + 1];
    if (e1 > e0) {
      float m = -1e30f;
      for (int j = e0; j < e1; ++j) m = fmaxf(m, esc[seid[j] * 4 + k]);
      float den = 0.f;
      for (int j = e0; j < e1; ++j) {
        float pv = expf(esc[seid[j] * 4 + k] - m);
        esc[seid[j] * 4 + k] = pv;
        den += pv;
      }
      float inv = 1.f / (den + 1e-16f);
      for (int j = e0; j < e1; ++j) esc[seid[j] * 4 + k] *= inv;
    }
  }
  __syncthreads();

  // ---- phase 4: layer-1 aggregate -> h1 into sA (f32); reload att2 ----
  satt[tid] = att2[tid];   // att1 dead (sync above separates)
  {
    int o = tid, k = o >> 6;
    float w0 = sWl1[o], w1 = sWl1[256 + o], w2 = sWl1[512 + o], w3 = sWl1[768 + o];
    for (int n = 0; n < NN; ++n) {
      int e0 = soff[n], e1 = soff[n + 1];
      float acc = 0.f;
      for (int j = e0; j < e1; ++j) {
        int e = seid[j];
        int s = ssrc[e];
        float xl = fmaf(sx[s * 4 + 3], w3, fmaf(sx[s * 4 + 2], w2,
                   fmaf(sx[s * 4 + 1], w1, sx[s * 4 + 0] * w0)));
        acc = fmaf(esc[e * 4 + k], xl, acc);
      }
      float ov = acc + sbias[o];
      sA[n * KH + o] = fmaxf(ov, 0.f);   // relu(h1)
    }
  }
  __syncthreads();
  if (tid < NH) sbias[tid] = b2[tid];   // b1 dead

  // ---- phase 5: layer-2 transforms: thread owns output column o = tid ----
  float axl[NN], axr[NN];
#pragma unroll
  for (int n = 0; n < NN; ++n) { axl[n] = 0.f; axr[n] = 0.f; }
  {
    const float* wlr = WlT + (size_t)tid * 256;
    const float* wrr = WrT + (size_t)tid * 256;
    for (int ic = 0; ic < 32; ++ic) {
      const float4* wl4 = (const float4*)(wlr + ic * 8);
      const float4* wr4 = (const float4*)(wrr + ic * 8);
      float4 la = wl4[0], lb = wl4[1], ra = wr4[0], rb = wr4[1];
      float wl[8] = {la.x, la.y, la.z, la.w, lb.x, lb.y, lb.z, lb.w};
      float wr[8] = {ra.x, ra.y, ra.z, ra.w, rb.x, rb.y, rb.z, rb.w};
#pragma unroll
      for (int n = 0; n < NN; ++n) {
        const float4* hp = (const float4*)&sA[n * 256 + ic * 8];
        float4 ha = hp[0], hb = hp[1];
        float hv[8] = {ha.x, ha.y, ha.z, ha.w, hb.x, hb.y, hb.z, hb.w};
#pragma unroll
        for (int q = 0; q < 8; ++q) {
          axl[n] = fmaf(hv[q], wl[q], axl[n]);
          axr[n] = fmaf(hv[q], wr[q], axr[n]);
        }
      }
    }
  }
  __syncthreads();
  // overwrite sA region with bf16 xl | xr (exactly 49152 B)
  u16* xlb = (u16*)sA;
  u16* xrb = xlb + NN * KH;
#pragma unroll
  for (int n = 0; n < NN; ++n) {
    xlb[n * 256 + tid] = f2bf(axl[n]);
    xrb[n * 256 + tid] = f2bf(axr[n]);
  }
  __syncthreads();

  // ---- phase 6: layer-2 edge scores ----
  for (int task = tid; task < NE * NK; task += 256) {
    int e = task >> 2, k = task & 3;
    int s = ssrc[e], d = sdst[e];
    const u16* xls = xlb + s * 256 + k * 64;
    const u16* xrd = xrb + d * 256 + k * 64;
    const float* ap = satt + k * 64;
    float acc = 0.f;
    for (int h = 0; h < 64; ++h) {
      float tv = bf2f(xls[h]) + bf2f(xrd[h]);
      tv = tv > 0.f ? tv : 0.2f * tv;
      acc = fmaf(tv, ap[h], acc);
    }
    esc[e * 4 + k] = acc;
  }
  __syncthreads();

  // ---- phase 7: layer-2 softmax ----
  if (tid < NN * NK) {
    int n = tid >> 2, k = tid & 3;
    int e0 = soff[n], e1 = soff[n + 1];
    if (e1 > e0) {
      float m = -1e30f;
      for (int j = e0; j < e1; ++j) m = fmaxf(m, esc[seid[j] * 4 + k]);
      float den = 0.f;
      for (int j = e0; j < e1; ++j) {
        float pv = expf(esc[seid[j] * 4 + k] - m);
        esc[seid[j] * 4 + k] = pv;
        den += pv;
      }
      float inv = 1.f / (den + 1e-16f);
      for (int j = e0; j < e1; ++j) esc[seid[j] * 4 + k] *= inv;
    }
  }
  __syncthreads();

  // ---- phase 8: layer-2 aggregate, mean over k, +bias, relu -> h2 (f32) ----
  for (int task = tid; task < NN * NH; task += 256) {
    int n = task >> 6, h = task & 63;
    int e0 = soff[n], e1 = soff[n + 1];
    float acc = 0.f;
    for (int j = e0; j < e1; ++j) {
      int e = seid[j];
      int s = ssrc[e];
      const u16* xls = xlb + s * 256 + h;
#pragma unroll
      for (int k = 0; k < 4; ++k)
        acc = fmaf(esc[e * 4 + k], bf2f(xls[k * 64]), acc);
    }
    float ov = fmaf(acc, 0.25f, sbias[h]);
    h2[(size_t)g * SEQD + task] = fmaxf(ov, 0.f);
  }
}

// ---------------- kernel 3: xw = seq @ W_ih^T + (b_ih+b_hh), all f32 --------
// 64g x 64r tile, 256 threads; grid = 16 gtiles * 32 rtiles = 512 blocks.
__global__ __launch_bounds__(256) void xw_kernel(const float* __restrict__ h2,
                                                 const float* __restrict__ Wih,
                                                 const float* __restrict__ bih,
                                                 const float* __restrict__ bhh,
                                                 float* __restrict__ xw)
{
  __shared__ float sseq[96 * 64];   // [i][g]
  __shared__ float sw[96 * 64];     // [i][r]
  const int tid = threadIdx.x;
  const int gt = blockIdx.x & 15;
  const int rt = blockIdx.x >> 4;
  const int g0 = gt * 64, r0 = rt * 64;
  const int r = tid & 63, gsub = tid >> 6;   // gsub<4, 16 g each
  const int R = r0 + r;
  const int lane = tid & 63, qi = tid >> 6;  // staging: 4 chunks x 24 i
  float acc[16];
#pragma unroll
  for (int j = 0; j < 16; ++j) acc[j] = 0.f;

  for (int ic = 0; ic < 32; ++ic) {
    __syncthreads();
    {
      const float* src = h2 + (size_t)(g0 + lane) * SEQD + ic * 96 + qi * 24;
#pragma unroll
      for (int q = 0; q < 24; ++q) sseq[(qi * 24 + q) * 64 + lane] = src[q];
    }
    {
      const float* wsrc = Wih + (size_t)(r0 + lane) * SEQD + ic * 96 + qi * 24;
#pragma unroll
      for (int q = 0; q < 24; ++q) sw[(qi * 24 + q) * 64 + lane] = wsrc[q];
    }
    __syncthreads();
    for (int i = 0; i < 96; ++i) {
      float wv = sw[i * 64 + r];
      const float4* sp = (const float4*)&sseq[i * 64 + gsub * 16];
      float4 s0 = sp[0], s1 = sp[1], s2 = sp[2], s3 = sp[3];
      float sv[16] = {s0.x, s0.y, s0.z, s0.w, s1.x, s1.y, s1.z, s1.w,
                      s2.x, s2.y, s2.z, s2.w, s3.x, s3.y, s3.z, s3.w};
#pragma unroll
      for (int j = 0; j < 16; ++j) acc[j] = fmaf(sv[j], wv, acc[j]);
    }
  }
  const float bias = bih[R] + bhh[R];
#pragma unroll
  for (int j = 0; j < 16; ++j) {
    int g = g0 + gsub * 16 + j;
    xw[(size_t)g * G4 + R] = acc[j] + bias;
  }
}

// ---------------- kernel 4: persistent LSTM + FC, stamped-flag sync ---------
// 64 blocks x 256 threads. Per-block flag stamps step progress; all h/flag
// traffic is agent-scope (memory-side coherent) -> no fences, no L2 flushes.
__global__ __launch_bounds__(256) void lstm_kernel(const float* __restrict__ xw,
                                                   const float* __restrict__ Whh,
                                                   const float* __restrict__ fcw,
                                                   const float* __restrict__ fcb,
                                                   float* hbuf,
                                                   int* flags,
                                                   float* __restrict__ out)
{
  __shared__ float hlds[NB * NLH];     // 8KB
  __shared__ float part[8][32][4];
  __shared__ float gv[32][4];
  __shared__ float clds[8][4];
  __shared__ float fcpart[32][8];

  const int tid = threadIdx.x;
  const int blk = blockIdx.x;
  const int r32 = tid & 31, p = tid >> 5;
  const int R = (r32 >> 3) * NLH + blk * 8 + (r32 & 7);  // gate row owned

  float wreg[64];                       // Whh row R, segment p*64..p*64+63
  {
    const float4* wsrc = (const float4*)(Whh + (size_t)R * NLH + p * 64);
#pragma unroll
    for (int q = 0; q < 16; ++q) {
      float4 v = wsrc[q];
      wreg[4 * q + 0] = v.x; wreg[4 * q + 1] = v.y;
      wreg[4 * q + 2] = v.z; wreg[4 * q + 3] = v.w;
    }
  }
  // h_0 = 0 slice (agent-scope stores; same wave as the flag store below)
  if (tid < 32) {
    int u = tid & 7, b = tid >> 3;
    clds[u][b] = 0.f;
    __hip_atomic_store(&hbuf[0 * (NB * NLH) + b * NLH + blk * 8 + u], 0.f,
                       __ATOMIC_RELAXED, __HIP_MEMORY_SCOPE_AGENT);
  }
  if (tid == 0)
    __hip_atomic_store(&flags[blk * FLAG_STRIDE], 0,
                       __ATOMIC_RELEASE, __HIP_MEMORY_SCOPE_AGENT);

  for (int s = 0; s < NT; ++s) {
    // xw slice for this step: independent of h, issue before the poll
    float myxw = 0.f;
    if (tid < 128) {
      int rrx = tid & 31, b = tid >> 5;
      int Rx = (rrx >> 3) * NLH + blk * 8 + (rrx & 7);
      myxw = xw[(size_t)(b * NT + s) * G4 + Rx];
    }
    // wait: all 64 flags >= s (wave 0 polls, one flag per lane)
    if (tid < 64) {
      while (true) {
        int v = __hip_atomic_load(&flags[tid * FLAG_STRIDE],
                                  __ATOMIC_RELAXED, __HIP_MEMORY_SCOPE_AGENT);
        if (__all(v >= s)) break;
        __builtin_amdgcn_s_sleep(1);
      }
    }
    __syncthreads();
    // stage h_s (buf s&1) into LDS via agent-scope loads
    {
      float* hsrc = hbuf + (s & 1) * (NB * NLH);
#pragma unroll
      for (int w = 0; w < 8; ++w) {
        int idx = w * 256 + tid;
        hlds[idx] = __hip_atomic_load(&hsrc[idx],
                                      __ATOMIC_RELAXED, __HIP_MEMORY_SCOPE_AGENT);
      }
    }
    __syncthreads();

    float a0 = 0.f, a1 = 0.f, a2 = 0.f, a3 = 0.f;
    const float* h0 = &hlds[0 * NLH + p * 64];
    const float* h1p = &hlds[1 * NLH + p * 64];
    const float* h2p = &hlds[2 * NLH + p * 64];
    const float* h3p = &hlds[3 * NLH + p * 64];
#pragma unroll
    for (int j = 0; j < 16; ++j) {
      float w0 = wreg[4 * j], w1 = wreg[4 * j + 1], w2 = wreg[4 * j + 2], w3 = wreg[4 * j + 3];
      float4 v0 = *(const float4*)(h0 + 4 * j);
      float4 v1 = *(const float4*)(h1p + 4 * j);
      float4 v2 = *(const float4*)(h2p + 4 * j);
      float4 v3 = *(const float4*)(h3p + 4 * j);
      a0 = fmaf(v0.w, w3, fmaf(v0.z, w2, fmaf(v0.y, w1, fmaf(v0.x, w0, a0))));
      a1 = fmaf(v1.w, w3, fmaf(v1.z, w2, fmaf(v1.y, w1, fmaf(v1.x, w0, a1))));
      a2 = fmaf(v2.w, w3, fmaf(v2.z, w2, fmaf(v2.y, w1, fmaf(v2.x, w0, a2))));
      a3 = fmaf(v3.w, w3, fmaf(v3.z, w2, fmaf(v3.y, w1, fmaf(v3.x, w0, a3))));
    }
    part[p][r32][0] = a0; part[p][r32][1] = a1;
    part[p][r32][2] = a2; part[p][r32][3] = a3;
    __syncthreads();
    if (tid < 128) {
      int rrx = tid & 31, b = tid >> 5;
      float sum = myxw;
#pragma unroll
      for (int pp = 0; pp < 8; ++pp) sum += part[pp][rrx][b];
      gv[rrx][b] = sum;
    }
    __syncthreads();
    if (tid < 32) {
      int u = tid & 7, b = tid >> 3;
      float gi = gv[0 + u][b], gf = gv[8 + u][b], gg = gv[16 + u][b], go = gv[24 + u][b];
      float si = 1.f / (1.f + expf(-gi));
      float sf = 1.f / (1.f + expf(-gf));
      float so = 1.f / (1.f + expf(-go));
      float cn = fmaf(sf, clds[u][b], si * tanhf(gg));
      float hn = so * tanhf(cn);
      clds[u][b] = cn;
      __hip_atomic_store(&hbuf[((s + 1) & 1) * (NB * NLH) + b * NLH + blk * 8 + u], hn,
                         __ATOMIC_RELAXED, __HIP_MEMORY_SCOPE_AGENT);
    }
    // release-stamp: same wave (lane 0) as the 32 h-stores above -> ordered
    if (tid == 0)
      __hip_atomic_store(&flags[blk * FLAG_STRIDE], s + 1,
                         __ATOMIC_RELEASE, __HIP_MEMORY_SCOPE_AGENT);
  }

  // FC on block 0; final h_NT is in buf[NT&1] = buf[0]
  if (blk == 0) {
    if (tid < 64) {
      while (true) {
        int v = __hip_atomic_load(&flags[tid * FLAG_STRIDE],
                                  __ATOMIC_RELAXED, __HIP_MEMORY_SCOPE_AGENT);
        if (__all(v >= NT)) break;
        __builtin_amdgcn_s_sleep(1);
      }
    }
    __syncthreads();
    {
      float* hsrc = hbuf + (NT & 1) * (NB * NLH);
#pragma unroll
      for (int w = 0; w < 8; ++w) {
        int idx = w * 256 + tid;
        hlds[idx] = __hip_atomic_load(&hsrc[idx],
                                      __ATOMIC_RELAXED, __HIP_MEMORY_SCOPE_AGENT);
      }
    }
    __syncthreads();
    int pr = tid >> 3, l = tid & 7;
    int b = pr >> 3, cc = pr & 7;
    const float* hf = hlds + b * NLH;
    float a = 0.f;
    int base = cc * NLH + l * 64;
    for (int j = 0; j < 64; ++j) a = fmaf(hf[l * 64 + j], fcw[base + j], a);
    fcpart[pr][l] = a;
    __syncthreads();
    if (tid < 32) {
      float s = fcb[tid & 7];
#pragma unroll
      for (int l2 = 0; l2 < 8; ++l2) s += fcpart[tid][l2];
      out[tid] = s;
    }
  }
}

// ---------------- host ----------------
extern "C" void kernel_launch(void* const* d_in, const int* in_sizes, int n_in,
                              void* d_out, int out_size, void* d_ws, size_t ws_size,
                              hipStream_t stream)
{
  (void)in_sizes; (void)n_in; (void)out_size; (void)ws_size;
  const float* x    = (const float*)d_in[0];
  const int*   ei   = (const int*)d_in[1];
  const float* Wl1  = (const float*)d_in[2];
  const float* Wr1  = (const float*)d_in[3];
  const float* att1 = (const float*)d_in[4];
  const float* b1   = (const float*)d_in[5];
  const float* Wl2  = (const float*)d_in[6];
  const float* Wr2  = (const float*)d_in[7];
  const float* att2 = (const float*)d_in[8];
  const float* b2   = (const float*)d_in[9];
  const float* Wih  = (const float*)d_in[10];
  const float* Whh  = (const float*)d_in[11];
  const float* bih  = (const float*)d_in[12];
  const float* bhh  = (const float*)d_in[13];
  const float* fcw  = (const float*)d_in[14];
  const float* fcb  = (const float*)d_in[15];

  // workspace layout (~21.5 MB)
  char* ws = (char*)d_ws;
  int* csr_off = (int*)(ws + 0);                    // 49 ints
  int* csr_eid = (int*)(ws + 256);                  // 192 ints -> ends 1024
  int* flags   = (int*)(ws + 1024);                 // 64 * 64B = 4096 -> 5120
  float* WlT   = (float*)(ws + 8192);               // 256 KB -> 270336
  float* WrT   = (float*)(ws + 270336);             // 256 KB -> 532480
  float* h2    = (float*)(ws + 532480);             // 12 MB  -> 13115392
  float* xwb   = (float*)(ws + 13115392);           // 8 MB   -> 21504000
  float* hbuf  = (float*)(ws + 21504000);           // 16 KB  -> 21520384
  float* outp  = (float*)d_out;

  setup_kernel<<<1, 64, 0, stream>>>(ei, csr_off, csr_eid, flags);
  transpose_kernel<<<128, 256, 0, stream>>>(Wl2, Wr2, WlT, WrT);
  gat_fused_kernel<<<NG, 256, 0, stream>>>(x, ei, csr_off, csr_eid,
                                           Wl1, Wr1, att1, b1,
                                           WlT, WrT, att2, b2, h2);
  xw_kernel<<<512, 256, 0, stream>>>(h2, Wih, bih, bhh, xwb);
  lstm_kernel<<<LSTM_NBLK, 256, 0, stream>>>(xwb, Whh, fcw, fcb, hbuf, flags, outp);
}

// Round 6
// 1631.703 us; speedup vs baseline: 2.8322x; 1.4019x over previous
//
#include <hip/hip_runtime.h>
#include <math.h>

typedef unsigned short u16;
typedef unsigned int u32;
typedef unsigned long long u64;

// dims
#define NB 4
#define NT 256
#define NN 48
#define NF 4
#define NH 64
#define NK 4
#define NE 192
#define NLH 512
#define NC 8
#define NG 1024          // B*T
#define KH 256           // K*H
#define SEQD 3072        // N*H
#define G4 2048          // 4*LH
#define LSTM_NBLK 64

__device__ __forceinline__ float bf2f(u16 v) {
  union { u32 u; float f; } c; c.u = ((u32)v) << 16; return c.f;
}
__device__ __forceinline__ u16 f2bf(float f) {
  union { float f; u32 u; } c; c.f = f;
  u32 r = c.u + 0x7FFFu + ((c.u >> 16) & 1u);
  return (u16)(r >> 16);
}
__device__ __forceinline__ u32 fbits(float f) { union { float f; u32 u; } c; c.f = f; return c.u; }
__device__ __forceinline__ float bitsf(u32 u) { union { u32 u; float f; } c; c.u = u; return c.f; }

// ---------------- kernel 0: CSR build (by dst) ----------------
__global__ void setup_kernel(const int* __restrict__ ei, int* __restrict__ coff,
                             int* __restrict__ ceid)
{
  if (threadIdx.x == 0 && blockIdx.x == 0) {
    int cnt[NN];
    for (int n = 0; n < NN; ++n) cnt[n] = 0;
    for (int e = 0; e < NE; ++e) cnt[ei[NE + e]]++;
    coff[0] = 0;
    for (int n = 0; n < NN; ++n) coff[n + 1] = coff[n] + cnt[n];
    int pos[NN];
    for (int n = 0; n < NN; ++n) pos[n] = coff[n];
    for (int e = 0; e < NE; ++e) { int d = ei[NE + e]; ceid[pos[d]++] = e; }
  }
}

// ---------------- kernel 0b: transpose Wl2/Wr2 -> [out][in] (f32) -----------
__global__ void transpose_kernel(const float* __restrict__ Wl2, const float* __restrict__ Wr2,
                                 float* __restrict__ WlT, float* __restrict__ WrT)
{
  int id0 = blockIdx.x * 256 + threadIdx.x;
  for (int rep = 0; rep < 2; ++rep) {
    int id = id0 + rep * 32768;               // id = o*256 + i
    int o = id >> 8, i = id & 255;
    WlT[id] = Wl2[i * 256 + o];
    WrT[id] = Wr2[i * 256 + o];
  }
}

// ---------------- kernel 1: fused GATv2 layer1+layer2 (one block per graph) --
// All-f32 except xl/xr packed bf16 in LDS (fits 64KB static limit).
__global__ __launch_bounds__(256) void gat_fused_kernel(
    const float* __restrict__ x, const int* __restrict__ ei,
    const int* __restrict__ coff, const int* __restrict__ ceid,
    const float* __restrict__ Wl1, const float* __restrict__ Wr1,
    const float* __restrict__ att1, const float* __restrict__ b1,
    const float* __restrict__ WlT, const float* __restrict__ WrT,
    const float* __restrict__ att2, const float* __restrict__ b2,
    float* __restrict__ h2)
{
  __shared__ float sA[NN * KH];          // 48KB: h1 (f32), later xl|xr (bf16)
  __shared__ float sWl1[NF * KH], sWr1[NF * KH];   // 4KB + 4KB
  __shared__ float satt[KH];             // att1 then att2
  __shared__ float sbias[KH];            // b1 then b2
  __shared__ float sx[NN * NF];          // 768B
  __shared__ float esc[NE * NK];         // 3KB
  __shared__ int soff[NN + 1];           // 196B
  __shared__ u16 seid[NE], ssrc[NE], sdst[NE];   // 3*384B

  const int tid = threadIdx.x;
  const int g = blockIdx.x;

  // ---- stage phase-1 constants ----
#pragma unroll
  for (int rep = 0; rep < 4; ++rep) {
    int idx = rep * 256 + tid;
    sWl1[idx] = Wl1[idx];
    sWr1[idx] = Wr1[idx];
  }
  satt[tid] = att1[tid];
  sbias[tid] = b1[tid];
  if (tid < NN * NF) sx[tid] = x[(size_t)g * (NN * NF) + tid];
  if (tid < NE) {
    ssrc[tid] = (u16)ei[tid];
    sdst[tid] = (u16)ei[NE + tid];
    seid[tid] = (u16)ceid[tid];
  }
  if (tid < NN + 1) soff[tid] = coff[tid];
  __syncthreads();

  // ---- phase 2: layer-1 edge scores ----
  for (int task = tid; task < NE * NK; task += 256) {
    int e = task >> 2, k = task & 3;
    int s = ssrc[e], d = sdst[e];
    float xs0 = sx[s * 4 + 0], xs1 = sx[s * 4 + 1], xs2 = sx[s * 4 + 2], xs3 = sx[s * 4 + 3];
    float xd0 = sx[d * 4 + 0], xd1 = sx[d * 4 + 1], xd2 = sx[d * 4 + 2], xd3 = sx[d * 4 + 3];
    float acc = 0.f;
    int ob = k * 64;
    for (int h = 0; h < 64; ++h) {
      int o = ob + h;
      float xl = fmaf(xs3, sWl1[768 + o], fmaf(xs2, sWl1[512 + o],
                 fmaf(xs1, sWl1[256 + o], xs0 * sWl1[o])));
      float xr = fmaf(xd3, sWr1[768 + o], fmaf(xd2, sWr1[512 + o],
                 fmaf(xd1, sWr1[256 + o], xd0 * sWr1[o])));
      float tv = xl + xr;
      tv = tv > 0.f ? tv : 0.2f * tv;
      acc = fmaf(tv, satt[o], acc);
    }
    esc[e * 4 + k] = acc;
  }
  __syncthreads();

  // ---- phase 3: layer-1 softmax per (n,k) ----
  if (tid < NN * NK) {
    int n = tid >> 2, k = tid & 3;
    int e0 = soff[n], e1 = soff[n + 1];
    if (e1 > e0) {
      float m = -1e30f;
      for (int j = e0; j < e1; ++j) m = fmaxf(m, esc[seid[j] * 4 + k]);
      float den = 0.f;
      for (int j = e0; j < e1; ++j) {
        float pv = expf(esc[seid[j] * 4 + k] - m);
        esc[seid[j] * 4 + k] = pv;
        den += pv;
      }
      float inv = 1.f / (den + 1e-16f);
      for (int j = e0; j < e1; ++j) esc[seid[j] * 4 + k] *= inv;
    }
  }
  __syncthreads();

  // ---- phase 4: layer-1 aggregate -> h1 into sA (f32); reload att2 ----
  satt[tid] = att2[tid];   // att1 dead (sync above separates)
  {
    int o = tid, k = o >> 6;
    float w0 = sWl1[o], w1 = sWl1[256 + o], w2 = sWl1[512 + o], w3 = sWl1[768 + o];
    for (int n = 0; n < NN; ++n) {
      int e0 = soff[n], e1 = soff[n + 1];
      float acc = 0.f;
      for (int j = e0; j < e1; ++j) {
        int e = seid[j];
        int s = ssrc[e];
        float xl = fmaf(sx[s * 4 + 3], w3, fmaf(sx[s * 4 + 2], w2,
                   fmaf(sx[s * 4 + 1], w1, sx[s * 4 + 0] * w0)));
        acc = fmaf(esc[e * 4 + k], xl, acc);
      }
      float ov = acc + sbias[o];
      sA[n * KH + o] = fmaxf(ov, 0.f);   // relu(h1)
    }
  }
  __syncthreads();
  if (tid < NH) sbias[tid] = b2[tid];   // b1 dead

  // ---- phase 5: layer-2 transforms: thread owns output column o = tid ----
  float axl[NN], axr[NN];
#pragma unroll
  for (int n = 0; n < NN; ++n) { axl[n] = 0.f; axr[n] = 0.f; }
  {
    const float* wlr = WlT + (size_t)tid * 256;
    const float* wrr = WrT + (size_t)tid * 256;
    for (int ic = 0; ic < 32; ++ic) {
      const float4* wl4 = (const float4*)(wlr + ic * 8);
      const float4* wr4 = (const float4*)(wrr + ic * 8);
      float4 la = wl4[0], lb = wl4[1], ra = wr4[0], rb = wr4[1];
      float wl[8] = {la.x, la.y, la.z, la.w, lb.x, lb.y, lb.z, lb.w};
      float wr[8] = {ra.x, ra.y, ra.z, ra.w, rb.x, rb.y, rb.z, rb.w};
#pragma unroll
      for (int n = 0; n < NN; ++n) {
        const float4* hp = (const float4*)&sA[n * 256 + ic * 8];
        float4 ha = hp[0], hb = hp[1];
        float hv[8] = {ha.x, ha.y, ha.z, ha.w, hb.x, hb.y, hb.z, hb.w};
#pragma unroll
        for (int q = 0; q < 8; ++q) {
          axl[n] = fmaf(hv[q], wl[q], axl[n]);
          axr[n] = fmaf(hv[q], wr[q], axr[n]);
        }
      }
    }
  }
  __syncthreads();
  // overwrite sA region with bf16 xl | xr (exactly 49152 B)
  u16* xlb = (u16*)sA;
  u16* xrb = xlb + NN * KH;
#pragma unroll
  for (int n = 0; n < NN; ++n) {
    xlb[n * 256 + tid] = f2bf(axl[n]);
    xrb[n * 256 + tid] = f2bf(axr[n]);
  }
  __syncthreads();

  // ---- phase 6: layer-2 edge scores ----
  for (int task = tid; task < NE * NK; task += 256) {
    int e = task >> 2, k = task & 3;
    int s = ssrc[e], d = sdst[e];
    const u16* xls = xlb + s * 256 + k * 64;
    const u16* xrd = xrb + d * 256 + k * 64;
    const float* ap = satt + k * 64;
    float acc = 0.f;
    for (int h = 0; h < 64; ++h) {
      float tv = bf2f(xls[h]) + bf2f(xrd[h]);
      tv = tv > 0.f ? tv : 0.2f * tv;
      acc = fmaf(tv, ap[h], acc);
    }
    esc[e * 4 + k] = acc;
  }
  __syncthreads();

  // ---- phase 7: layer-2 softmax ----
  if (tid < NN * NK) {
    int n = tid >> 2, k = tid & 3;
    int e0 = soff[n], e1 = soff[n + 1];
    if (e1 > e0) {
      float m = -1e30f;
      for (int j = e0; j < e1; ++j) m = fmaxf(m, esc[seid[j] * 4 + k]);
      float den = 0.f;
      for (int j = e0; j < e1; ++j) {
        float pv = expf(esc[seid[j] * 4 + k] - m);
        esc[seid[j] * 4 + k] = pv;
        den += pv;
      }
      float inv = 1.f / (den + 1e-16f);
      for (int j = e0; j < e1; ++j) esc[seid[j] * 4 + k] *= inv;
    }
  }
  __syncthreads();

  // ---- phase 8: layer-2 aggregate, mean over k, +bias, relu -> h2 (f32) ----
  for (int task = tid; task < NN * NH; task += 256) {
    int n = task >> 6, h = task & 63;
    int e0 = soff[n], e1 = soff[n + 1];
    float acc = 0.f;
    for (int j = e0; j < e1; ++j) {
      int e = seid[j];
      int s = ssrc[e];
      const u16* xls = xlb + s * 256 + h;
#pragma unroll
      for (int k = 0; k < 4; ++k)
        acc = fmaf(esc[e * 4 + k], bf2f(xls[k * 64]), acc);
    }
    float ov = fmaf(acc, 0.25f, sbias[h]);
    h2[(size_t)g * SEQD + task] = fmaxf(ov, 0.f);
  }
}

// ---------------- kernel 3: xw = seq @ W_ih^T + (b_ih+b_hh), all f32 --------
// 64g x 64r tile, 256 threads; grid = 16 gtiles * 32 rtiles = 512 blocks.
__global__ __launch_bounds__(256) void xw_kernel(const float* __restrict__ h2,
                                                 const float* __restrict__ Wih,
                                                 const float* __restrict__ bih,
                                                 const float* __restrict__ bhh,
                                                 float* __restrict__ xw)
{
  __shared__ float sseq[96 * 64];   // [i][g]
  __shared__ float sw[96 * 64];     // [i][r]
  const int tid = threadIdx.x;
  const int gt = blockIdx.x & 15;
  const int rt = blockIdx.x >> 4;
  const int g0 = gt * 64, r0 = rt * 64;
  const int r = tid & 63, gsub = tid >> 6;   // gsub<4, 16 g each
  const int R = r0 + r;
  const int lane = tid & 63, qi = tid >> 6;  // staging: 4 chunks x 24 i
  float acc[16];
#pragma unroll
  for (int j = 0; j < 16; ++j) acc[j] = 0.f;

  for (int ic = 0; ic < 32; ++ic) {
    __syncthreads();
    {
      const float* src = h2 + (size_t)(g0 + lane) * SEQD + ic * 96 + qi * 24;
#pragma unroll
      for (int q = 0; q < 24; ++q) sseq[(qi * 24 + q) * 64 + lane] = src[q];
    }
    {
      const float* wsrc = Wih + (size_t)(r0 + lane) * SEQD + ic * 96 + qi * 24;
#pragma unroll
      for (int q = 0; q < 24; ++q) sw[(qi * 24 + q) * 64 + lane] = wsrc[q];
    }
    __syncthreads();
    for (int i = 0; i < 96; ++i) {
      float wv = sw[i * 64 + r];
      const float4* sp = (const float4*)&sseq[i * 64 + gsub * 16];
      float4 s0 = sp[0], s1 = sp[1], s2 = sp[2], s3 = sp[3];
      float sv[16] = {s0.x, s0.y, s0.z, s0.w, s1.x, s1.y, s1.z, s1.w,
                      s2.x, s2.y, s2.z, s2.w, s3.x, s3.y, s3.z, s3.w};
#pragma unroll
      for (int j = 0; j < 16; ++j) acc[j] = fmaf(sv[j], wv, acc[j]);
    }
  }
  const float bias = bih[R] + bhh[R];
#pragma unroll
  for (int j = 0; j < 16; ++j) {
    int g = g0 + gsub * 16 + j;
    xw[(size_t)g * G4 + R] = acc[j] + bias;
  }
}

// ---------------- kernel 4: persistent LSTM + FC, self-validating pairs -----
// Each h value travels as one 8B atom [stamp:u32 | h-bits:u32]: the poll load
// IS the data load (2 LLC hops/step instead of 3+, no fences, no release).
// Wave w waits only on its own h segment [w*128, (w+1)*128) x 4 batches.
// Parity reuse is safe: a block stores h_{s+1} only after barriers A/B, i.e.
// after all its waves saw every stamp >= s -> all 64 blocks finished reading
// parity (s-1), which is the parity being overwritten.
__global__ __launch_bounds__(256) void lstm_kernel(const float* __restrict__ xw,
                                                   const float* __restrict__ Whh,
                                                   const float* __restrict__ fcw,
                                                   const float* __restrict__ fcb,
                                                   u64* pairs,
                                                   float* __restrict__ out)
{
  __shared__ float hlds[NB * NLH];     // 8KB
  __shared__ float part[8][32][4];
  __shared__ float gv[32][4];
  __shared__ float clds[8][4];
  __shared__ float fcpart[32][8];

  const int tid = threadIdx.x;
  const int blk = blockIdx.x;
  const int r32 = tid & 31, p = tid >> 5;
  const int lane = tid & 63, w = tid >> 6;
  const int R = (r32 >> 3) * NLH + blk * 8 + (r32 & 7);  // gate row owned

  float wreg[64];                       // Whh row R, segment p*64..p*64+63
  {
    const float4* wsrc = (const float4*)(Whh + (size_t)R * NLH + p * 64);
#pragma unroll
    for (int q = 0; q < 16; ++q) {
      float4 v = wsrc[q];
      wreg[4 * q + 0] = v.x; wreg[4 * q + 1] = v.y;
      wreg[4 * q + 2] = v.z; wreg[4 * q + 3] = v.w;
    }
  }
  // h_0 = 0 with stamp 0 (ws poison 0xAAAA.. has negative stamp = not-ready)
  if (tid < 32) {
    int u = tid & 7, b = tid >> 3;
    clds[u][b] = 0.f;
    __hip_atomic_store(&pairs[0 * (NB * NLH) + b * NLH + blk * 8 + u], 0ULL,
                       __ATOMIC_RELAXED, __HIP_MEMORY_SCOPE_AGENT);
  }

  for (int s = 0; s < NT; ++s) {
    // xw slice for this step: independent of h, issue before the poll
    float myxw = 0.f;
    if (tid < 128) {
      int rrx = tid & 31, b = tid >> 5;
      int Rx = (rrx >> 3) * NLH + blk * 8 + (rrx & 7);
      myxw = xw[(size_t)(b * NT + s) * G4 + Rx];
    }
    // poll-with-data: wave w fetches its 128 units x 4 batches, 8 pairs/lane
    {
      u64* pb = pairs + (size_t)(s & 1) * (NB * NLH);
      const int u0 = w * 128 + lane, u1 = u0 + 64;
      u64 v[8];
      while (true) {
#pragma unroll
        for (int b = 0; b < NB; ++b) {
          v[2 * b]     = __hip_atomic_load(&pb[b * NLH + u0],
                                           __ATOMIC_RELAXED, __HIP_MEMORY_SCOPE_AGENT);
          v[2 * b + 1] = __hip_atomic_load(&pb[b * NLH + u1],
                                           __ATOMIC_RELAXED, __HIP_MEMORY_SCOPE_AGENT);
        }
        int mn = 0x7fffffff;
#pragma unroll
        for (int q = 0; q < 8; ++q) mn = min(mn, (int)(u32)(v[q] >> 32));
        if (__all(mn >= s)) break;
      }
#pragma unroll
      for (int b = 0; b < NB; ++b) {
        hlds[b * NLH + u0] = bitsf((u32)v[2 * b]);
        hlds[b * NLH + u1] = bitsf((u32)v[2 * b + 1]);
      }
    }
    // no block barrier: wave w reads only hlds range it just wrote

    float a0 = 0.f, a1 = 0.f, a2 = 0.f, a3 = 0.f;
    const float* h0 = &hlds[0 * NLH + p * 64];
    const float* h1p = &hlds[1 * NLH + p * 64];
    const float* h2p = &hlds[2 * NLH + p * 64];
    const float* h3p = &hlds[3 * NLH + p * 64];
#pragma unroll
    for (int j = 0; j < 16; ++j) {
      float w0 = wreg[4 * j], w1 = wreg[4 * j + 1], w2 = wreg[4 * j + 2], w3 = wreg[4 * j + 3];
      float4 v0 = *(const float4*)(h0 + 4 * j);
      float4 v1 = *(const float4*)(h1p + 4 * j);
      float4 v2 = *(const float4*)(h2p + 4 * j);
      float4 v3 = *(const float4*)(h3p + 4 * j);
      a0 = fmaf(v0.w, w3, fmaf(v0.z, w2, fmaf(v0.y, w1, fmaf(v0.x, w0, a0))));
      a1 = fmaf(v1.w, w3, fmaf(v1.z, w2, fmaf(v1.y, w1, fmaf(v1.x, w0, a1))));
      a2 = fmaf(v2.w, w3, fmaf(v2.z, w2, fmaf(v2.y, w1, fmaf(v2.x, w0, a2))));
      a3 = fmaf(v3.w, w3, fmaf(v3.z, w2, fmaf(v3.y, w1, fmaf(v3.x, w0, a3))));
    }
    part[p][r32][0] = a0; part[p][r32][1] = a1;
    part[p][r32][2] = a2; part[p][r32][3] = a3;
    __syncthreads();                                  // barrier A
    if (tid < 128) {
      int rrx = tid & 31, b = tid >> 5;
      float sum = myxw;
#pragma unroll
      for (int pp = 0; pp < 8; ++pp) sum += part[pp][rrx][b];
      gv[rrx][b] = sum;
    }
    __syncthreads();                                  // barrier B
    if (tid < 32) {
      int u = tid & 7, b = tid >> 3;
      float gi = gv[0 + u][b], gf = gv[8 + u][b], gg = gv[16 + u][b], go = gv[24 + u][b];
      float si = 1.f / (1.f + expf(-gi));
      float sf = 1.f / (1.f + expf(-gf));
      float so = 1.f / (1.f + expf(-go));
      float cn = fmaf(sf, clds[u][b], si * tanhf(gg));
      float hn = so * tanhf(cn);
      clds[u][b] = cn;
      u64 pk = ((u64)(u32)(s + 1) << 32) | (u64)fbits(hn);
      __hip_atomic_store(&pairs[(size_t)((s + 1) & 1) * (NB * NLH) + b * NLH + blk * 8 + u],
                         pk, __ATOMIC_RELAXED, __HIP_MEMORY_SCOPE_AGENT);
    }
  }

  // FC on block 0; final h_NT is in parity NT&1 = 0 with stamp NT
  if (blk == 0) {
    {
      u64* pb = pairs + (size_t)(NT & 1) * (NB * NLH);
      const int u0 = w * 128 + lane, u1 = u0 + 64;
      u64 v[8];
      while (true) {
#pragma unroll
        for (int b = 0; b < NB; ++b) {
          v[2 * b]     = __hip_atomic_load(&pb[b * NLH + u0],
                                           __ATOMIC_RELAXED, __HIP_MEMORY_SCOPE_AGENT);
          v[2 * b + 1] = __hip_atomic_load(&pb[b * NLH + u1],
                                           __ATOMIC_RELAXED, __HIP_MEMORY_SCOPE_AGENT);
        }
        int mn = 0x7fffffff;
#pragma unroll
        for (int q = 0; q < 8; ++q) mn = min(mn, (int)(u32)(v[q] >> 32));
        if (__all(mn >= NT)) break;
      }
#pragma unroll
      for (int b = 0; b < NB; ++b) {
        hlds[b * NLH + u0] = bitsf((u32)v[2 * b]);
        hlds[b * NLH + u1] = bitsf((u32)v[2 * b + 1]);
      }
    }
    __syncthreads();   // FC reads across all waves' staged segments
    int pr = tid >> 3, l = tid & 7;
    int b = pr >> 3, cc = pr & 7;
    const float* hf = hlds + b * NLH;
    float a = 0.f;
    int base = cc * NLH + l * 64;
    for (int j = 0; j < 64; ++j) a = fmaf(hf[l * 64 + j], fcw[base + j], a);
    fcpart[pr][l] = a;
    __syncthreads();
    if (tid < 32) {
      float s = fcb[tid & 7];
#pragma unroll
      for (int l2 = 0; l2 < 8; ++l2) s += fcpart[tid][l2];
      out[tid] = s;
    }
  }
}

// ---------------- host ----------------
extern "C" void kernel_launch(void* const* d_in, const int* in_sizes, int n_in,
                              void* d_out, int out_size, void* d_ws, size_t ws_size,
                              hipStream_t stream)
{
  (void)in_sizes; (void)n_in; (void)out_size; (void)ws_size;
  const float* x    = (const float*)d_in[0];
  const int*   ei   = (const int*)d_in[1];
  const float* Wl1  = (const float*)d_in[2];
  const float* Wr1  = (const float*)d_in[3];
  const float* att1 = (const float*)d_in[4];
  const float* b1   = (const float*)d_in[5];
  const float* Wl2  = (const float*)d_in[6];
  const float* Wr2  = (const float*)d_in[7];
  const float* att2 = (const float*)d_in[8];
  const float* b2   = (const float*)d_in[9];
  const float* Wih  = (const float*)d_in[10];
  const float* Whh  = (const float*)d_in[11];
  const float* bih  = (const float*)d_in[12];
  const float* bhh  = (const float*)d_in[13];
  const float* fcw  = (const float*)d_in[14];
  const float* fcb  = (const float*)d_in[15];

  // workspace layout (~21.6 MB)
  char* ws = (char*)d_ws;
  int* csr_off = (int*)(ws + 0);                    // 49 ints
  int* csr_eid = (int*)(ws + 256);                  // 192 ints -> ends 1024
  u64* pairs   = (u64*)(ws + 1024);                 // 2*2048*8B = 32KB -> 33792
  float* WlT   = (float*)(ws + 40960);              // 256 KB -> 303104
  float* WrT   = (float*)(ws + 303104);             // 256 KB -> 565248
  float* h2    = (float*)(ws + 565248);             // 12 MB  -> 13148160
  float* xwb   = (float*)(ws + 13148160);           // 8 MB   -> 21536768
  float* outp  = (float*)d_out;

  setup_kernel<<<1, 64, 0, stream>>>(ei, csr_off, csr_eid);
  transpose_kernel<<<128, 256, 0, stream>>>(Wl2, Wr2, WlT, WrT);
  gat_fused_kernel<<<NG, 256, 0, stream>>>(x, ei, csr_off, csr_eid,
                                           Wl1, Wr1, att1, b1,
                                           WlT, WrT, att2, b2, h2);
  xw_kernel<<<512, 256, 0, stream>>>(h2, Wih, bih, bhh, xwb);
  lstm_kernel<<<LSTM_NBLK, 256, 0, stream>>>(xwb, Whh, fcw, fcb, pairs, outp);
}